// Round 1
// baseline (1039.277 us; speedup 1.0000x reference)
//
#include <hip/hip_runtime.h>

typedef _Float16 half8 __attribute__((ext_vector_type(8)));
typedef _Float16 half4 __attribute__((ext_vector_type(4)));
typedef float floatx4 __attribute__((ext_vector_type(4)));

// ---------------- workspace layout (bytes) ----------------
// X fp16 region [0, 134217728) is dead after the projection GEMM; S/P alias it.
#define OFF_X    0L
#define OFF_S    0L                      // 4 batches * 2048*2048 fp32 = 67108864
#define OFF_P    67108864L               // 4 batches * 2048*2048 fp16 = 33554432
#define OFF_W    134217728L              // 1024*1024 fp16 = 2097152
#define OFF_QK   136314880L              // 65536*1024 fp16 = 134217728 (Q rows 0.., K rows 32768..)
#define OFF_KT   270532608L              // 16*1024*2048 fp16 = 67108864
#define OFF_MASK 337641472L              // 32768 u8
#define WS_NEED  337674240L

__device__ __forceinline__ void glds16(const void* g, void* l) {
  __builtin_amdgcn_global_load_lds(
      (__attribute__((address_space(1))) void*)(void*)(g),
      (__attribute__((address_space(3))) void*)(l), 16, 0, 0);
}

// ---------------- mask canonicalization ----------------
// Robust to the bool arriving as u8 (1B) or int32 (4B). Single block.
__global__ void mask_canon(const unsigned* __restrict__ raw,
                           unsigned char* __restrict__ outm) {
  __shared__ int flag;
  int t = threadIdx.x;
  if (t == 0) flag = 0;
  __syncthreads();
  int loc = 0;
  for (int i = t; i < 8192; i += 256)      // 32KB scan: whole u8 array / first 1/4 of i32
    if (raw[i] > 1u) loc = 1;
  if (loc) flag = 1;                        // benign race
  __syncthreads();
  if (flag) {                               // u8 storage
    const unsigned char* b8 = (const unsigned char*)raw;
    for (int j = t; j < 32768; j += 256) outm[j] = (b8[j] != 0);
  } else {                                  // i32 storage
    const int* r32 = (const int*)raw;
    for (int j = t; j < 32768; j += 256) outm[j] = (r32[j] != 0);
  }
}

// ---------------- fp32 -> fp16 convert ----------------
__global__ __launch_bounds__(256) void cvt_f32_f16(const float* __restrict__ x,
                                                   _Float16* __restrict__ y, long n) {
  long i = ((long)blockIdx.x * 256 + threadIdx.x) * 4;
  if (i + 3 < n) {
    float4 v = *(const float4*)(x + i);
    half4 h;
    h[0] = (_Float16)v.x; h[1] = (_Float16)v.y;
    h[2] = (_Float16)v.z; h[3] = (_Float16)v.w;
    *(half4*)(y + i) = h;
  }
}

// ---------------- NT GEMM skeleton ----------------
// C[m,n] = sum_k A[m,k]*B[n,k]; A row stride == K, B row stride == K.
// EPI=true: C fp16, +bias[n], relu.  EPI=false: C fp32 raw.
// Tile 128x128, BK=64, 256 threads (2x2 waves of 64x64), 16x16x32 f16 MFMA.
// LDS rows are 128B = 8 chunks of 16B, chunk XOR-swizzled by (row&7).
template <bool EPI>
__global__ __launch_bounds__(256, 3)
void gemm_nt(const _Float16* __restrict__ A, long sAz,
             const _Float16* __restrict__ B, long sBz,
             void* __restrict__ Cv, long sCz,
             const float* __restrict__ bias, int K, int ldc) {
  __shared__ _Float16 As[128 * 64];
  __shared__ _Float16 Bs[128 * 64];
  const int t = threadIdx.x;
  const int l = t & 63;
  const int w = t >> 6;
  A += (long)blockIdx.z * sAz + (long)blockIdx.y * 128 * K;
  B += (long)blockIdx.z * sBz + (long)blockIdx.x * 128 * K;
  const int waveM = (w >> 1) * 64, waveN = (w & 1) * 64;
  const int l15 = l & 15, quad = l >> 4;
  const int srow = l >> 3;
  const int gchunk = (l & 7) ^ (srow & 7);

  floatx4 acc[4][4] = {};

  for (int kt = 0; kt < K; kt += 64) {
    __syncthreads();
#pragma unroll
    for (int c = 0; c < 4; c++) {
      const int r = w * 32 + c * 8;
      glds16(A + (long)(r + srow) * K + kt + gchunk * 8, As + r * 64);
      glds16(B + (long)(r + srow) * K + kt + gchunk * 8, Bs + r * 64);
    }
    __syncthreads();
#pragma unroll
    for (int k32 = 0; k32 < 2; k32++) {
      half8 af[4], bfr[4];
#pragma unroll
      for (int mi = 0; mi < 4; mi++) {
        const int r = waveM + mi * 16 + l15;
        const int cc = (k32 * 4 + quad) ^ (r & 7);
        af[mi] = *(const half8*)(As + r * 64 + cc * 8);
      }
#pragma unroll
      for (int ni = 0; ni < 4; ni++) {
        const int r = waveN + ni * 16 + l15;
        const int cc = (k32 * 4 + quad) ^ (r & 7);
        bfr[ni] = *(const half8*)(Bs + r * 64 + cc * 8);
      }
#pragma unroll
      for (int mi = 0; mi < 4; mi++)
#pragma unroll
        for (int ni = 0; ni < 4; ni++)
          acc[mi][ni] = __builtin_amdgcn_mfma_f32_16x16x32_f16(af[mi], bfr[ni],
                                                               acc[mi][ni], 0, 0, 0);
    }
  }

  const int rowb = quad * 4;
  if constexpr (EPI) {
    _Float16* Cp = (_Float16*)Cv + (long)blockIdx.z * sCz +
                   (long)blockIdx.y * 128 * ldc + blockIdx.x * 128;
#pragma unroll
    for (int mi = 0; mi < 4; mi++)
#pragma unroll
      for (int ni = 0; ni < 4; ni++) {
        const int col = waveN + ni * 16 + l15;
        const float bv = bias[blockIdx.x * 128 + col];
#pragma unroll
        for (int p = 0; p < 4; p++) {
          const int row = waveM + mi * 16 + rowb + p;
          Cp[(long)row * ldc + col] = (_Float16)fmaxf(acc[mi][ni][p] + bv, 0.f);
        }
      }
  } else {
    float* Cp = (float*)Cv + (long)blockIdx.z * sCz +
                (long)blockIdx.y * 128 * ldc + blockIdx.x * 128;
#pragma unroll
    for (int mi = 0; mi < 4; mi++)
#pragma unroll
      for (int ni = 0; ni < 4; ni++) {
        const int col = waveN + ni * 16 + l15;
#pragma unroll
        for (int p = 0; p < 4; p++) {
          const int row = waveM + mi * 16 + rowb + p;
          Cp[(long)row * ldc + col] = acc[mi][ni][p];
        }
      }
  }
}

// ---------------- K transpose (per batch, fp16) ----------------
// Km: rows (b*2048+j) x 1024(h)  ->  KT[b][h][j] rows 1024 x 2048
__global__ __launch_bounds__(256) void transpose_k(const _Float16* __restrict__ Km,
                                                   _Float16* __restrict__ KT) {
  __shared__ _Float16 tile[64 * 72];
  const int t = threadIdx.x;
  const long b = blockIdx.z;
  const _Float16* src = Km + (b * 2048 + blockIdx.x * 64) * 1024 + blockIdx.y * 64;
  {
    const int jl = t >> 2, hc = (t & 3) * 16;
    half8 v0 = *(const half8*)(src + (long)jl * 1024 + hc);
    half8 v1 = *(const half8*)(src + (long)jl * 1024 + hc + 8);
    *(half8*)&tile[jl * 72 + hc] = v0;
    *(half8*)&tile[jl * 72 + hc + 8] = v1;
  }
  __syncthreads();
  {
    const int hl = t >> 2, jc = (t & 3) * 16;
    half8 o0, o1;
#pragma unroll
    for (int jj = 0; jj < 8; jj++) o0[jj] = tile[(jc + jj) * 72 + hl];
#pragma unroll
    for (int jj = 0; jj < 8; jj++) o1[jj] = tile[(jc + 8 + jj) * 72 + hl];
    long off = (b * 1024 + blockIdx.y * 64 + hl) * 2048 + blockIdx.x * 64 + jc;
    *(half8*)(KT + off) = o0;
    *(half8*)(KT + off + 8) = o1;
  }
}

// ---------------- masked softmax: S fp32 row -> P fp16 row ----------------
__global__ __launch_bounds__(256) void softmax_k(const float* __restrict__ S,
                                                 _Float16* __restrict__ P,
                                                 const unsigned char* __restrict__ mask,
                                                 int b0) {
  const int i = blockIdx.x, z = blockIdx.y, t = threadIdx.x;
  const float* s = S + ((long)z * 2048 + i) * 2048;
  const unsigned char* mrow = mask + (long)(b0 + z) * 2048;
  const int base0 = t * 4, base1 = 1024 + t * 4;
  float4 a0 = *(const float4*)(s + base0);
  float4 a1 = *(const float4*)(s + base1);
  float v[8] = {a0.x, a0.y, a0.z, a0.w, a1.x, a1.y, a1.z, a1.w};
  const float NINF = -__builtin_inff();
#pragma unroll
  for (int k = 0; k < 4; k++) {
    if (mrow[base0 + k]) v[k] = NINF;
    if (mrow[base1 + k]) v[4 + k] = NINF;
  }
  float mx = v[0];
#pragma unroll
  for (int k = 1; k < 8; k++) mx = fmaxf(mx, v[k]);
#pragma unroll
  for (int o = 32; o >= 1; o >>= 1) mx = fmaxf(mx, __shfl_xor(mx, o, 64));
  __shared__ float redm[4], reds[4];
  if ((t & 63) == 0) redm[t >> 6] = mx;
  __syncthreads();
  mx = fmaxf(fmaxf(redm[0], redm[1]), fmaxf(redm[2], redm[3]));
  float e[8], sm = 0.f;
#pragma unroll
  for (int k = 0; k < 8; k++) { e[k] = __expf(v[k] - mx); sm += e[k]; }
#pragma unroll
  for (int o = 32; o >= 1; o >>= 1) sm += __shfl_xor(sm, o, 64);
  if ((t & 63) == 0) reds[t >> 6] = sm;
  __syncthreads();
  sm = reds[0] + reds[1] + reds[2] + reds[3];
  const float inv = 1.0f / sm;   // never a fully-masked row
  _Float16* p = P + ((long)z * 2048 + i) * 2048;
  half4 h0, h1;
#pragma unroll
  for (int k = 0; k < 4; k++) { h0[k] = (_Float16)(e[k] * inv); h1[k] = (_Float16)(e[4 + k] * inv); }
  *(half4*)(p + base0) = h0;
  *(half4*)(p + base1) = h1;
}

extern "C" void kernel_launch(void* const* d_in, const int* in_sizes, int n_in,
                              void* d_out, int out_size, void* d_ws, size_t ws_size,
                              hipStream_t stream) {
  (void)in_sizes; (void)n_in; (void)out_size;
  if ((long)ws_size < WS_NEED) return;  // workspace too small: leave out poisoned as a clear signal

  const float* inp  = (const float*)d_in[0];
  const float* ctx  = (const float*)d_in[1];
  const unsigned* msk = (const unsigned*)d_in[2];
  const float* W    = (const float*)d_in[3];
  const float* bias = (const float*)d_in[4];
  float* out = (float*)d_out;
  char* ws = (char*)d_ws;

  _Float16* Xf   = (_Float16*)(ws + OFF_X);
  float*    Sb   = (float*)(ws + OFF_S);
  _Float16* Pb   = (_Float16*)(ws + OFF_P);
  _Float16* Wf   = (_Float16*)(ws + OFF_W);
  _Float16* QK   = (_Float16*)(ws + OFF_QK);
  _Float16* KT   = (_Float16*)(ws + OFF_KT);
  unsigned char* Mc = (unsigned char*)(ws + OFF_MASK);

  // 1. canonical mask
  mask_canon<<<1, 256, 0, stream>>>(msk, Mc);
  // 2. fp32 -> fp16 (inp | ctx | W)
  cvt_f32_f16<<<32768, 256, 0, stream>>>(inp, Xf, 33554432L);
  cvt_f32_f16<<<32768, 256, 0, stream>>>(ctx, Xf + 33554432L, 33554432L);
  cvt_f32_f16<<<1024, 256, 0, stream>>>(W, Wf, 1048576L);
  // 3. projection: QK = relu([inp;ctx] @ W^T + b), M=65536, N=1024, K=1024
  gemm_nt<true><<<dim3(8, 512, 1), 256, 0, stream>>>(Xf, 0L, Wf, 0L, (void*)QK, 0L,
                                                     bias, 1024, 1024);
  // 4. K^T per batch
  transpose_k<<<dim3(32, 16, 16), 256, 0, stream>>>(QK + 32768L * 1024, KT);
  // 5. per 4-batch quad: scores -> softmax -> PV
  for (int bp = 0; bp < 4; bp++) {
    const _Float16* Aq = QK + (long)bp * 4 * 2048 * 1024;
    const _Float16* Bk = QK + (32768L + (long)bp * 4 * 2048) * 1024;
    gemm_nt<false><<<dim3(16, 16, 4), 256, 0, stream>>>(Aq, 2048L * 1024, Bk, 2048L * 1024,
                                                        (void*)Sb, 2048L * 2048, nullptr,
                                                        1024, 2048);
    softmax_k<<<dim3(2048, 4), 256, 0, stream>>>(Sb, Pb, Mc, bp * 4);
    gemm_nt<false><<<dim3(8, 16, 4), 256, 0, stream>>>(Pb, 2048L * 2048,
                                                       KT + (long)bp * 4 * 1024 * 2048,
                                                       1024L * 2048,
                                                       (void*)(out + (long)bp * 4 * 2048 * 1024),
                                                       2048L * 1024, nullptr, 2048, 1024);
  }
}